// Round 3
// baseline (233.875 us; speedup 1.0000x reference)
//
#include <hip/hip_runtime.h>

#define SEQ_LEN 64
#define BATCH   262144

// One Anki scheduler step, exactly mirroring the JAX reference arithmetic.
// `first` corresponds to jnp.all(state == 0): globally true only at t==0
// (after step 0, ease is clipped to >= 1.3, so the state array can never be
// all-zero again).
__device__ __forceinline__ void anki_step(bool first, float dt, float rating,
                                          float& ivl, float& ease,
                                          float w0, float w1, float w2, float w3,
                                          float w4, float w5, float w6)
{
    float days_late = dt - ivl;
    float elapsed   = ivl + days_late;

    float m = fmaxf(elapsed * ease, ivl);
    float early = (rating == 2.0f) ? fmaxf(elapsed * w4, ivl * w4 * 0.5f)
                : (rating == 4.0f) ? m
                :                    m * (w3 - (w3 - 1.0f) * 0.5f);

    float nonearly = (rating == 2.0f) ? ivl * w4
                   : (rating == 4.0f) ? (ivl + days_late * 0.5f) * ease
                   :                    (ivl + days_late) * ease * w3;

    float upd_ivl = (rating == 1.0f) ? ivl * w5
                  : ((days_late < 0.0f) ? early : nonearly) * w6;

    float upd_ease = (rating == 1.0f) ? ease - 0.2f
                   : (rating == 2.0f) ? ease - 0.15f
                   : (rating == 4.0f) ? ease + 0.15f
                   :                    ease;

    float init_ivl = (rating < 4.0f) ? w0 : w1;

    float ni = first ? init_ivl : upd_ivl;
    float ne = first ? w2       : upd_ease;

    // clip ease
    ne = fminf(fmaxf(ne, 1.3f), 5.5f);

    // new_ivl = clip(max(leaky_relu(ni - 1) + 1, ni), S_MIN, S_MAX)
    float x  = ni - 1.0f;
    float lr = (x >= 0.0f) ? x : 0.01f * x;     // jax.nn.leaky_relu slope 0.01
    ni = fminf(fmaxf(fmaxf(lr + 1.0f, ni), 0.01f), 36500.0f);

    ivl  = ni;
    ease = ne;
}

__global__ __launch_bounds__(256) void anki_scan(const float2* __restrict__ in,
                                                 const float*  __restrict__ w,
                                                 float2*       __restrict__ out)
{
    const int b = blockIdx.x * 256 + threadIdx.x;

    // w is uniform across all lanes -> compiler emits scalar loads
    const float w0 = w[0], w1 = w[1], w2 = w[2], w3 = w[3],
                w4 = w[4], w5 = w[5], w6 = w[6];

    float ivl = 0.0f, ease = 0.0f;

    // t = 0: global is_zero path
    {
        float2 x = in[b];
        anki_step(true, x.x, x.y, ivl, ease, w0, w1, w2, w3, w4, w5, w6);
        out[b] = make_float2(ivl, ease);
    }

    // t = 1 .. 63: loads are independent of the state chain; unroll so the
    // compiler keeps multiple global_load_dwordx2 in flight per wave.
    #pragma unroll 8
    for (int t = 1; t < SEQ_LEN; ++t) {
        float2 x = in[(size_t)t * BATCH + b];
        anki_step(false, x.x, x.y, ivl, ease, w0, w1, w2, w3, w4, w5, w6);
        out[(size_t)t * BATCH + b] = make_float2(ivl, ease);
    }

    // final_state, appended after the (64, B, 2) outputs
    out[(size_t)SEQ_LEN * BATCH + b] = make_float2(ivl, ease);
}

extern "C" void kernel_launch(void* const* d_in, const int* in_sizes, int n_in,
                              void* d_out, int out_size, void* d_ws, size_t ws_size,
                              hipStream_t stream)
{
    const float2* in = (const float2*)d_in[0];   // (64, 262144, 2) f32
    const float*  w  = (const float*)d_in[1];    // (7,) f32
    float2*       out = (float2*)d_out;          // outputs (64,B,2) ++ final (B,2)

    anki_scan<<<BATCH / 256, 256, 0, stream>>>(in, w, out);
}